// Round 17
// baseline (45.965 us; speedup 1.0000x reference)
//
#include <hip/hip_runtime.h>
#include <math.h>

#define BB 16
#define TT 128
#define MM 32
#define PP 64
#define CC 256

typedef float f32x4 __attribute__((ext_vector_type(4)));

// ---- K1: per (b,m), 512 threads: w_in, eff_c(+nrm), eff_p, matvec, MLP ----
__global__ __launch_bounds__(512) void K1_front(
        const float* __restrict__ pointers,
        const float* __restrict__ contents,
        const float* __restrict__ receivers,
        const float* __restrict__ memories,
        const float* __restrict__ W1,
        const float* __restrict__ b1,
        const float* __restrict__ W2,
        const float* __restrict__ b2,
        float* __restrict__ nrm_ws,
        float* __restrict__ outp_g,
        float* __restrict__ outc_g) {
    const int bm = blockIdx.x;
    const int b = bm >> 5, m = bm & 31;
    const int tid = threadIdx.x;
    const int lane = tid & 63, w = tid >> 6;

    __shared__ float w_in[TT];
    __shared__ __align__(16) float ri[PP + CC];   // [eff_p | eff_c]
    __shared__ float partc[4][CC];
    __shared__ float part8[8][PP];
    __shared__ float h[PP];
    __shared__ float outc_s[CC];
    __shared__ float red[4];

    // ---- w_in: 4 lanes per token, contiguous float4 reads ----
    {
        const int t = tid >> 2, q = tid & 3;
        const float4* pr4 = reinterpret_cast<const float4*>(pointers + (b * TT + t) * PP + q * 16);
        const float4* rc4 = reinterpret_cast<const float4*>(receivers + m * PP + q * 16);
        float s = 0.f;
        #pragma unroll
        for (int k = 0; k < 4; ++k) {
            float4 v = pr4[k], rv = rc4[k];
            s += v.x * rv.x + v.y * rv.y + v.z * rv.z + v.w * rv.w;
        }
        s += __shfl_xor(s, 1, 64);
        s += __shfl_xor(s, 2, 64);
        if (q == 0) {
            float th = tanhf(s);
            w_in[t] = th > 0.f ? th : 0.f;
        }
    }
    __syncthreads();
    // ---- eff_c partials: float2 column-pairs, 4 t-groups of 32 ----
    {
        const int cp = tid & 127, g = tid >> 7;
        const float2* cb2 = reinterpret_cast<const float2*>(contents + (b * TT + g * 32) * CC) + cp;
        float2 acc = {0.f, 0.f};
        #pragma unroll 8
        for (int t = 0; t < 32; ++t) {
            float2 v = cb2[t * 128];
            const float ww = w_in[g * 32 + t];
            acc.x += ww * v.x;
            acc.y += ww * v.y;
        }
        partc[g][2 * cp]     = acc.x;
        partc[g][2 * cp + 1] = acc.y;
    }
    // ---- eff_p partials: p = tid&63, 8 t-groups of 16 ----
    {
        const int p = tid & 63, g = tid >> 6;
        const float* pb = pointers + (b * TT + g * 16) * PP + p;
        float acc = 0.f;
        #pragma unroll
        for (int t = 0; t < 16; ++t) acc += w_in[g * 16 + t] * pb[t * PP];
        part8[g][p] = acc;
    }
    __syncthreads();
    float ecv = 0.f;
    if (tid < CC) {
        ecv = partc[0][tid] + partc[1][tid] + partc[2][tid] + partc[3][tid];
        ri[PP + tid] = ecv;
        float v = ecv * ecv;
        #pragma unroll
        for (int off = 32; off; off >>= 1) v += __shfl_xor(v, off, 64);
        if (lane == 0) red[w] = v;
    } else if (tid < CC + PP) {
        const int p = tid - CC;
        float a = 0.f;
        #pragma unroll
        for (int g = 0; g < 8; ++g) a += part8[g][p];
        ri[p] = a;
    }
    __syncthreads();
    if (tid < CC) {
        const float ss = red[0] + red[1] + red[2] + red[3];
        nrm_ws[bm * CC + tid] = ecv / (ss + 1e-42f);
    }

    // ---- out_c = mem[m] @ eff_c: 16 lanes/row, 4 rows per wave-iter ----
    {
        const int g = lane >> 4, j = lane & 15;
        float4 e_reg[4];
        #pragma unroll
        for (int k = 0; k < 4; ++k)
            e_reg[k] = *reinterpret_cast<const float4*>(&ri[PP + 4 * (j + 16 * k)]);
        const float4* mem4 = reinterpret_cast<const float4*>(memories) + m * (CC * CC / 4);
        #pragma unroll
        for (int i = 0; i < 8; ++i) {
            const int c = w * 32 + i * 4 + g;
            const float4* row4 = mem4 + c * 64;
            float s = 0.f;
            #pragma unroll
            for (int k = 0; k < 4; ++k) {
                float4 mv = row4[j + 16 * k];
                s += mv.x * e_reg[k].x + mv.y * e_reg[k].y
                   + mv.z * e_reg[k].z + mv.w * e_reg[k].w;
            }
            s += __shfl_xor(s, 1, 64);
            s += __shfl_xor(s, 2, 64);
            s += __shfl_xor(s, 4, 64);
            s += __shfl_xor(s, 8, 64);
            if (j == 0) outc_s[c] = s;
        }
    }

    // ---- MLP layer 1 ----
    {
        const float* w1 = W1 + m * 320 * 64;
        float acc = 0.f;
        const int i0 = w * 40;
        #pragma unroll 8
        for (int i = i0; i < i0 + 40; ++i) acc += ri[i] * w1[i * 64 + lane];
        __syncthreads();               // also covers outc_s completion
        part8[w][lane] = acc;
    }
    __syncthreads();
    if (tid < PP) {
        float s = b1[m * PP + tid];
        #pragma unroll
        for (int g = 0; g < 8; ++g) s += part8[g][tid];
        h[tid] = s > 0.f ? s : 0.f;
    }
    __syncthreads();
    // ---- MLP layer 2 ----
    {
        const float* w2 = W2 + m * 64 * 64;
        float acc = 0.f;
        const int i0 = w * 8;
        #pragma unroll
        for (int i = i0; i < i0 + 8; ++i) acc += h[i] * w2[i * 64 + lane];
        part8[w][lane] = acc;
    }
    __syncthreads();
    if (tid < PP) {
        float s = b2[m * PP + tid];
        #pragma unroll
        for (int g = 0; g < 8; ++g) s += part8[g][tid];
        outp_g[bm * PP + tid] = s > 0.f ? s : 0.f;
    }
    if (tid < CC) outc_g[bm * CC + tid] = outc_s[tid];
}

// ---- K3: fill-like stream, batch-parallel prologue. grid = 512 (2/CU).
// Block owns one (m,cs) 64-row tile in 16 f32x4 regs. Phase A: wout rows for
// all 4 batches (no syncs). Phase B: eoc slices for all 4 (no syncs). 2 syncs
// total. Phase C: 4 back-to-back pure-store passes.
__global__ __launch_bounds__(256) void K3_fused(
        const float* __restrict__ memories,
        const float* __restrict__ outp_g,
        const float* __restrict__ outc_g,
        const float* __restrict__ nrm_ws,
        float* __restrict__ mems_out) {
    const int gid0 = blockIdx.x;           // [0, 512)
    const int b0 = gid0 >> 7;              // [0, 4)
    const int m = (gid0 >> 2) & 31, cs = gid0 & 3;
    const int tid = threadIdx.x;
    const int lane = tid & 63, w = tid >> 6;

    __shared__ float wout_s[4][MM];
    __shared__ float eoc_s[4][64];

    // ---- tile load ONCE into registers ----
    const f32x4* mem4 = reinterpret_cast<const f32x4*>(memories) + (m * CC + cs * 64) * 64;
    f32x4 mv[16];
    #pragma unroll
    for (int k = 0; k < 16; ++k) mv[k] = mem4[k * 256 + tid];

    // ---- nrm vectors for all 4 batches (independent loads) ----
    float4 nv[4];
    #pragma unroll
    for (int k4 = 0; k4 < 4; ++k4) {
        const int bm = (b0 + 4 * k4) * MM + m;
        nv[k4] = *reinterpret_cast<const float4*>(nrm_ws + bm * CC + lane * 4);
    }

    // ---- phase A: wout rows, 4 batches, independent chains ----
    {
        const int n = tid >> 3, j = tid & 7;
        #pragma unroll
        for (int k4 = 0; k4 < 4; ++k4) {
            const int b = b0 + 4 * k4;
            const float* opm = outp_g + (b * MM + m) * PP + j * 8;
            const float* opn = outp_g + (b * MM + n) * PP + j * 8;
            float s = 0.f;
            #pragma unroll
            for (int k = 0; k < 8; ++k) s += opm[k] * opn[k];
            s += __shfl_xor(s, 1, 64);
            s += __shfl_xor(s, 2, 64);
            s += __shfl_xor(s, 4, 64);
            if (j == 0) {
                float th = tanhf(s);
                wout_s[k4][n] = th > 0.f ? th : 0.f;
            }
        }
    }
    __syncthreads();
    // ---- phase B: eoc slices, 4 batches, independent ----
    {
        const int c_local = tid >> 2, k = tid & 3;
        const int c = cs * 64 + c_local;
        #pragma unroll
        for (int k4 = 0; k4 < 4; ++k4) {
            const int b = b0 + 4 * k4;
            const float* cb = outc_g + (b * MM + k * 8) * CC + c;
            float s = 0.f;
            #pragma unroll
            for (int kk = 0; kk < 8; ++kk)
                s += wout_s[k4][k * 8 + kk] * cb[kk * CC];
            s += __shfl_xor(s, 1, 64);
            s += __shfl_xor(s, 2, 64);
            if (k == 0) eoc_s[k4][c_local] = s;
        }
    }
    __syncthreads();

    // ---- phase C: 4 pure-store passes, no syncs ----
    #pragma unroll
    for (int k4 = 0; k4 < 4; ++k4) {
        const int bm = (b0 + 4 * k4) * MM + m;
        f32x4* out4 = reinterpret_cast<f32x4*>(mems_out) + (bm * CC + cs * 64) * 64;
        #pragma unroll
        for (int k = 0; k < 16; ++k) {
            const float e = eoc_s[k4][k * 4 + w];
            f32x4 o;
            o.x = 0.5f * (mv[k].x + e * nv[k4].x);
            o.y = 0.5f * (mv[k].y + e * nv[k4].y);
            o.z = 0.5f * (mv[k].z + e * nv[k4].z);
            o.w = 0.5f * (mv[k].w + e * nv[k4].w);
            out4[k * 256 + tid] = o;
        }
    }
}

extern "C" void kernel_launch(void* const* d_in, const int* in_sizes, int n_in,
                              void* d_out, int out_size, void* d_ws, size_t ws_size,
                              hipStream_t stream) {
    const float* pointers  = (const float*)d_in[0];
    const float* contents  = (const float*)d_in[1];
    const float* receivers = (const float*)d_in[2];
    const float* memories  = (const float*)d_in[3];
    const float* W1 = (const float*)d_in[4];
    const float* b1 = (const float*)d_in[5];
    const float* W2 = (const float*)d_in[6];
    const float* b2 = (const float*)d_in[7];

    float* out      = (float*)d_out;
    float* outp_g   = out;                       // 16*32*64
    float* outc_g   = out + 32768;               // 16*32*256
    float* mems_out = out + 32768 + 131072;      // 16*32*256*256

    float* nrm = (float*)d_ws;                   // 131072 floats

    hipLaunchKernelGGL(K1_front, dim3(BB * MM), dim3(512), 0, stream,
                       pointers, contents, receivers, memories, W1, b1, W2, b2,
                       nrm, outp_g, outc_g);
    hipLaunchKernelGGL(K3_fused, dim3(512), dim3(256), 0, stream,
                       memories, outp_g, outc_g, nrm, mems_out);
}

// Round 18
// 43.641 us; speedup vs baseline: 1.0532x; 1.0532x over previous
//
#include <hip/hip_runtime.h>
#include <math.h>

#define BB 16
#define TT 128
#define MM 32
#define PP 64
#define CC 256

typedef float f32x4 __attribute__((ext_vector_type(4)));

// ---- K1: per (b,m), 512 threads: w_in, eff_c(+nrm), eff_p, matvec, MLP ----
__global__ __launch_bounds__(512) void K1_front(
        const float* __restrict__ pointers,
        const float* __restrict__ contents,
        const float* __restrict__ receivers,
        const float* __restrict__ memories,
        const float* __restrict__ W1,
        const float* __restrict__ b1,
        const float* __restrict__ W2,
        const float* __restrict__ b2,
        float* __restrict__ nrm_ws,
        float* __restrict__ outp_g,
        float* __restrict__ outc_g) {
    const int bm = blockIdx.x;
    const int b = bm >> 5, m = bm & 31;
    const int tid = threadIdx.x;
    const int lane = tid & 63, w = tid >> 6;

    __shared__ float w_in[TT];
    __shared__ __align__(16) float ri[PP + CC];   // [eff_p | eff_c]
    __shared__ float partc[4][CC];
    __shared__ float part8[8][PP];
    __shared__ float h[PP];
    __shared__ float outc_s[CC];
    __shared__ float red[4];

    // ---- w_in: 4 lanes per token, contiguous float4 reads ----
    {
        const int t = tid >> 2, q = tid & 3;
        const float4* pr4 = reinterpret_cast<const float4*>(pointers + (b * TT + t) * PP + q * 16);
        const float4* rc4 = reinterpret_cast<const float4*>(receivers + m * PP + q * 16);
        float s = 0.f;
        #pragma unroll
        for (int k = 0; k < 4; ++k) {
            float4 v = pr4[k], rv = rc4[k];
            s += v.x * rv.x + v.y * rv.y + v.z * rv.z + v.w * rv.w;
        }
        s += __shfl_xor(s, 1, 64);
        s += __shfl_xor(s, 2, 64);
        if (q == 0) {
            float th = tanhf(s);
            w_in[t] = th > 0.f ? th : 0.f;
        }
    }
    __syncthreads();
    // ---- eff_c partials: float2 column-pairs, 4 t-groups of 32 ----
    {
        const int cp = tid & 127, g = tid >> 7;
        const float2* cb2 = reinterpret_cast<const float2*>(contents + (b * TT + g * 32) * CC) + cp;
        float2 acc = {0.f, 0.f};
        #pragma unroll 8
        for (int t = 0; t < 32; ++t) {
            float2 v = cb2[t * 128];
            const float ww = w_in[g * 32 + t];
            acc.x += ww * v.x;
            acc.y += ww * v.y;
        }
        partc[g][2 * cp]     = acc.x;
        partc[g][2 * cp + 1] = acc.y;
    }
    // ---- eff_p partials: p = tid&63, 8 t-groups of 16 ----
    {
        const int p = tid & 63, g = tid >> 6;
        const float* pb = pointers + (b * TT + g * 16) * PP + p;
        float acc = 0.f;
        #pragma unroll
        for (int t = 0; t < 16; ++t) acc += w_in[g * 16 + t] * pb[t * PP];
        part8[g][p] = acc;
    }
    __syncthreads();
    float ecv = 0.f;
    if (tid < CC) {
        ecv = partc[0][tid] + partc[1][tid] + partc[2][tid] + partc[3][tid];
        ri[PP + tid] = ecv;
        float v = ecv * ecv;
        #pragma unroll
        for (int off = 32; off; off >>= 1) v += __shfl_xor(v, off, 64);
        if (lane == 0) red[w] = v;
    } else if (tid < CC + PP) {
        const int p = tid - CC;
        float a = 0.f;
        #pragma unroll
        for (int g = 0; g < 8; ++g) a += part8[g][p];
        ri[p] = a;
    }
    __syncthreads();
    if (tid < CC) {
        const float ss = red[0] + red[1] + red[2] + red[3];
        nrm_ws[bm * CC + tid] = ecv / (ss + 1e-42f);
    }

    // ---- out_c = mem[m] @ eff_c: 16 lanes/row, 4 rows per wave-iter ----
    {
        const int g = lane >> 4, j = lane & 15;
        float4 e_reg[4];
        #pragma unroll
        for (int k = 0; k < 4; ++k)
            e_reg[k] = *reinterpret_cast<const float4*>(&ri[PP + 4 * (j + 16 * k)]);
        const float4* mem4 = reinterpret_cast<const float4*>(memories) + m * (CC * CC / 4);
        #pragma unroll
        for (int i = 0; i < 8; ++i) {
            const int c = w * 32 + i * 4 + g;
            const float4* row4 = mem4 + c * 64;
            float s = 0.f;
            #pragma unroll
            for (int k = 0; k < 4; ++k) {
                float4 mv = row4[j + 16 * k];
                s += mv.x * e_reg[k].x + mv.y * e_reg[k].y
                   + mv.z * e_reg[k].z + mv.w * e_reg[k].w;
            }
            s += __shfl_xor(s, 1, 64);
            s += __shfl_xor(s, 2, 64);
            s += __shfl_xor(s, 4, 64);
            s += __shfl_xor(s, 8, 64);
            if (j == 0) outc_s[c] = s;
        }
    }

    // ---- MLP layer 1 ----
    {
        const float* w1 = W1 + m * 320 * 64;
        float acc = 0.f;
        const int i0 = w * 40;
        #pragma unroll 8
        for (int i = i0; i < i0 + 40; ++i) acc += ri[i] * w1[i * 64 + lane];
        __syncthreads();               // also covers outc_s completion
        part8[w][lane] = acc;
    }
    __syncthreads();
    if (tid < PP) {
        float s = b1[m * PP + tid];
        #pragma unroll
        for (int g = 0; g < 8; ++g) s += part8[g][tid];
        h[tid] = s > 0.f ? s : 0.f;
    }
    __syncthreads();
    // ---- MLP layer 2 ----
    {
        const float* w2 = W2 + m * 64 * 64;
        float acc = 0.f;
        const int i0 = w * 8;
        #pragma unroll
        for (int i = i0; i < i0 + 8; ++i) acc += h[i] * w2[i * 64 + lane];
        part8[w][lane] = acc;
    }
    __syncthreads();
    if (tid < PP) {
        float s = b2[m * PP + tid];
        #pragma unroll
        for (int g = 0; g < 8; ++g) s += part8[g][tid];
        outp_g[bm * PP + tid] = s > 0.f ? s : 0.f;
    }
    if (tid < CC) outc_g[bm * CC + tid] = outc_s[tid];
}

// ---- K3: fill-like stream + software-pipelined prologue. grid = 512 (2/CU).
// Block owns one (m,cs) 64-row tile in 16 f32x4 regs; per batch k4:
// compute wout/eoc from PREFETCHED regs, prefetch batch k4+1, store pass.
__global__ __launch_bounds__(256) void K3_fused(
        const float* __restrict__ memories,
        const float* __restrict__ outp_g,
        const float* __restrict__ outc_g,
        const float* __restrict__ nrm_ws,
        float* __restrict__ mems_out) {
    const int gid0 = blockIdx.x;           // [0, 512)
    const int b0 = gid0 >> 7;              // [0, 4)
    const int m = (gid0 >> 2) & 31, cs = gid0 & 3;
    const int tid = threadIdx.x;
    const int lane = tid & 63, w = tid >> 6;
    const int n = tid >> 3, j = tid & 7;           // wout mapping
    const int c_local = tid >> 2, kq = tid & 3;    // eoc mapping
    const int c = cs * 64 + c_local;

    __shared__ float wout_s[MM];
    __shared__ float eoc_s[64];

    // ---- tile load ONCE into registers ----
    const f32x4* mem4 = reinterpret_cast<const f32x4*>(memories) + (m * CC + cs * 64) * 64;
    f32x4 mv[16];
    #pragma unroll
    for (int k = 0; k < 16; ++k) mv[k] = mem4[k * 256 + tid];

    // ---- prefetch registers for one batch in flight ----
    f32x4 opm0, opm1, opn0, opn1;
    float cbr[8];
    float4 nvr;
    {   // prefetch batch b0
        const int b = b0;
        const float* opm = outp_g + (b * MM + m) * PP + j * 8;
        const float* opn = outp_g + (b * MM + n) * PP + j * 8;
        opm0 = *reinterpret_cast<const f32x4*>(opm);
        opm1 = *reinterpret_cast<const f32x4*>(opm + 4);
        opn0 = *reinterpret_cast<const f32x4*>(opn);
        opn1 = *reinterpret_cast<const f32x4*>(opn + 4);
        const float* cb = outc_g + (b * MM + kq * 8) * CC + c;
        #pragma unroll
        for (int kk = 0; kk < 8; ++kk) cbr[kk] = cb[kk * CC];
        nvr = *reinterpret_cast<const float4*>(nrm_ws + (b * MM + m) * CC + lane * 4);
    }

    for (int k4 = 0; k4 < 4; ++k4) {
        const int b = b0 + 4 * k4;
        const int bm = b * MM + m;

        // ---- wout row m from prefetched regs ----
        {
            float s = opm0.x * opn0.x + opm0.y * opn0.y + opm0.z * opn0.z + opm0.w * opn0.w
                    + opm1.x * opn1.x + opm1.y * opn1.y + opm1.z * opn1.z + opm1.w * opn1.w;
            s += __shfl_xor(s, 1, 64);
            s += __shfl_xor(s, 2, 64);
            s += __shfl_xor(s, 4, 64);
            if (j == 0) {
                float th = tanhf(s);
                wout_s[n] = th > 0.f ? th : 0.f;
            }
        }
        __syncthreads();
        // ---- eoc slice from wout_s + prefetched cbr ----
        {
            float s = 0.f;
            #pragma unroll
            for (int kk = 0; kk < 8; ++kk)
                s += wout_s[kq * 8 + kk] * cbr[kk];
            s += __shfl_xor(s, 1, 64);
            s += __shfl_xor(s, 2, 64);
            if (kq == 0) eoc_s[c_local] = s;
        }
        const float4 nv_cur = nvr;         // copy before prefetch overwrites
        __syncthreads();

        // ---- prefetch next batch (hides under the store pass) ----
        if (k4 < 3) {
            const int bn = b0 + 4 * (k4 + 1);
            const float* opm = outp_g + (bn * MM + m) * PP + j * 8;
            const float* opn = outp_g + (bn * MM + n) * PP + j * 8;
            opm0 = *reinterpret_cast<const f32x4*>(opm);
            opm1 = *reinterpret_cast<const f32x4*>(opm + 4);
            opn0 = *reinterpret_cast<const f32x4*>(opn);
            opn1 = *reinterpret_cast<const f32x4*>(opn + 4);
            const float* cb = outc_g + (bn * MM + kq * 8) * CC + c;
            #pragma unroll
            for (int kk = 0; kk < 8; ++kk) cbr[kk] = cb[kk * CC];
            nvr = *reinterpret_cast<const float4*>(nrm_ws + (bn * MM + m) * CC + lane * 4);
        }

        // ---- pure-store pass: tile in registers ----
        f32x4* out4 = reinterpret_cast<f32x4*>(mems_out) + (bm * CC + cs * 64) * 64;
        #pragma unroll
        for (int k = 0; k < 16; ++k) {
            const float e = eoc_s[k * 4 + w];
            f32x4 o;
            o.x = 0.5f * (mv[k].x + e * nv_cur.x);
            o.y = 0.5f * (mv[k].y + e * nv_cur.y);
            o.z = 0.5f * (mv[k].z + e * nv_cur.z);
            o.w = 0.5f * (mv[k].w + e * nv_cur.w);
            out4[k * 256 + tid] = o;
        }
    }
}

extern "C" void kernel_launch(void* const* d_in, const int* in_sizes, int n_in,
                              void* d_out, int out_size, void* d_ws, size_t ws_size,
                              hipStream_t stream) {
    const float* pointers  = (const float*)d_in[0];
    const float* contents  = (const float*)d_in[1];
    const float* receivers = (const float*)d_in[2];
    const float* memories  = (const float*)d_in[3];
    const float* W1 = (const float*)d_in[4];
    const float* b1 = (const float*)d_in[5];
    const float* W2 = (const float*)d_in[6];
    const float* b2 = (const float*)d_in[7];

    float* out      = (float*)d_out;
    float* outp_g   = out;                       // 16*32*64
    float* outc_g   = out + 32768;               // 16*32*256
    float* mems_out = out + 32768 + 131072;      // 16*32*256*256

    float* nrm = (float*)d_ws;                   // 131072 floats

    hipLaunchKernelGGL(K1_front, dim3(BB * MM), dim3(512), 0, stream,
                       pointers, contents, receivers, memories, W1, b1, W2, b2,
                       nrm, outp_g, outc_g);
    hipLaunchKernelGGL(K3_fused, dim3(512), dim3(256), 0, stream,
                       memories, outp_g, outc_g, nrm, mems_out);
}